// Round 9
// baseline (62.481 us; speedup 1.0000x reference)
//
#include <hip/hip_runtime.h>
#include <hip/hip_fp16.h>

#define HW_PIX (1024*1024)
#define D_ATTR 16
#define V_VERTS 100000
#define F_FACES 200000
#define LDS_STRIDE 20   // 16 floats + 4 pad: keeps 16B alignment, spreads banks

typedef float f4 __attribute__((ext_vector_type(4)));
typedef unsigned int u4 __attribute__((ext_vector_type(4)));

// ---------- pre-pass kernels (run every call; deterministic) ----------

__global__ __launch_bounds__(256) void cvt_attr_kernel(
    const float* __restrict__ in, __half2* __restrict__ out) {
    int i = blockIdx.x * blockDim.x + threadIdx.x;
    const int n = V_VERTS * D_ATTR / 4;
    if (i >= n) return;
    f4 v = __builtin_nontemporal_load((const f4*)in + i);
    out[i*2 + 0] = __floats2half2_rn(v.x, v.y);
    out[i*2 + 1] = __floats2half2_rn(v.z, v.w);
}

__global__ __launch_bounds__(256) void pack_faces_kernel(
    const int* __restrict__ faces, unsigned long long* __restrict__ pf) {
    int i = blockIdx.x * blockDim.x + threadIdx.x;
    if (i >= F_FACES) return;
    unsigned long long v0 = (unsigned)__builtin_nontemporal_load(faces + i*3 + 0);
    unsigned long long v1 = (unsigned)__builtin_nontemporal_load(faces + i*3 + 1);
    unsigned long long v2 = (unsigned)__builtin_nontemporal_load(faces + i*3 + 2);
    pf[i] = v0 | (v1 << 17) | (v2 << 34);
}

// ---------- main kernel: 2 px/thread, 12 gathers in flight ----------

__device__ inline void cvt2(unsigned int w, float* f) {
    __half2 h = __builtin_bit_cast(__half2, w);
    float2 t = __half22float2(h);
    f[0] = t.x; f[1] = t.y;
}

__device__ inline void cvt8(u4 q, float* f) {
    cvt2(q.x, f + 0);
    cvt2(q.y, f + 2);
    cvt2(q.z, f + 4);
    cvt2(q.w, f + 6);
}

__global__ __launch_bounds__(256) void render_f16_kernel(
    const __half* __restrict__ attrH,               // V x 16 f16 (ws, L2-resident)
    const float* __restrict__ bary,                 // HW x 3 f32 (nt stream)
    const unsigned long long* __restrict__ pfaces,  // F packed (ws, L2-resident)
    const int* __restrict__ p2f,                    // HW int32 (nt stream)
    float* __restrict__ out,                        // HW x 16 f32 (nt, full-line)
    float* __restrict__ mask)                       // HW f32 (nt, dense)
{
    __shared__ __align__(16) float lds[256 * LDS_STRIDE];

    int tid = threadIdx.x;
    int base = blockIdx.x * 512;
    int i0 = base + tid;
    int i1 = base + 256 + tid;

    // ---- issue both pixels' index chains ----
    int pf0 = __builtin_nontemporal_load(p2f + i0);
    int pf1 = __builtin_nontemporal_load(p2f + i1);
    __builtin_nontemporal_store((pf0 != -1) ? 1.0f : 0.0f, mask + i0);
    __builtin_nontemporal_store((pf1 != -1) ? 1.0f : 0.0f, mask + i1);
    int fa = (pf0 < 0) ? pf0 + F_FACES : pf0;
    int fb = (pf1 < 0) ? pf1 + F_FACES : pf1;

    unsigned long long ua = pfaces[fa];
    unsigned long long ub = pfaces[fb];

    float b00 = __builtin_nontemporal_load(bary + i0*3 + 0);
    float b01 = __builtin_nontemporal_load(bary + i0*3 + 1);
    float b02 = __builtin_nontemporal_load(bary + i0*3 + 2);
    float b10 = __builtin_nontemporal_load(bary + i1*3 + 0);
    float b11 = __builtin_nontemporal_load(bary + i1*3 + 1);
    float b12 = __builtin_nontemporal_load(bary + i1*3 + 2);

    int v00 = (int)(ua & 0x1FFFF), v01 = (int)((ua >> 17) & 0x1FFFF), v02 = (int)((ua >> 34) & 0x1FFFF);
    int v10 = (int)(ub & 0x1FFFF), v11 = (int)((ub >> 17) & 0x1FFFF), v12 = (int)((ub >> 34) & 0x1FFFF);

    const u4* A00 = (const u4*)(attrH + (size_t)v00 * D_ATTR);
    const u4* A01 = (const u4*)(attrH + (size_t)v01 * D_ATTR);
    const u4* A02 = (const u4*)(attrH + (size_t)v02 * D_ATTR);
    const u4* A10 = (const u4*)(attrH + (size_t)v10 * D_ATTR);
    const u4* A11 = (const u4*)(attrH + (size_t)v11 * D_ATTR);
    const u4* A12 = (const u4*)(attrH + (size_t)v12 * D_ATTR);

    // ---- 12 gathers in flight ----
    u4 g00a = A00[0], g00b = A00[1];
    u4 g01a = A01[0], g01b = A01[1];
    u4 g02a = A02[0], g02b = A02[1];
    u4 g10a = A10[0], g10b = A10[1];
    u4 g11a = A11[0], g11b = A11[1];
    u4 g12a = A12[0], g12b = A12[1];

    float x0[16], x1[16], x2[16];

    // ---- pixel 0 compute ----
    cvt8(g00a, x0); cvt8(g00b, x0 + 8);
    cvt8(g01a, x1); cvt8(g01b, x1 + 8);
    cvt8(g02a, x2); cvt8(g02b, x2 + 8);
    float acc0[16];
    #pragma unroll
    for (int q = 0; q < 16; ++q)
        acc0[q] = b00*x0[q] + b01*x1[q] + b02*x2[q];

    // ---- pixel 1 compute ----
    cvt8(g10a, x0); cvt8(g10b, x0 + 8);
    cvt8(g11a, x1); cvt8(g11b, x1 + 8);
    cvt8(g12a, x2); cvt8(g12b, x2 + 8);
    float acc1[16];
    #pragma unroll
    for (int q = 0; q < 16; ++q)
        acc1[q] = b10*x0[q] + b11*x1[q] + b12*x2[q];

    // ---- half A: stage + transposed full-line nt store ----
    f4* o4 = (f4*)out + (size_t)blockIdx.x * 2048;   // 512 px * 4 quads

    #pragma unroll
    for (int q = 0; q < 4; ++q) {
        f4 r = { acc0[4*q], acc0[4*q+1], acc0[4*q+2], acc0[4*q+3] };
        *(f4*)&lds[tid * LDS_STRIDE + q * 4] = r;
    }
    __syncthreads();
    #pragma unroll
    for (int k = 0; k < 4; ++k) {
        int flat = k * 1024 + tid * 4;
        int pix  = flat >> 4;
        int e    = flat & 15;
        f4 v = *(const f4*)&lds[pix * LDS_STRIDE + e];
        __builtin_nontemporal_store(v, o4 + k * 256 + tid);
    }
    __syncthreads();

    // ---- half B ----
    #pragma unroll
    for (int q = 0; q < 4; ++q) {
        f4 r = { acc1[4*q], acc1[4*q+1], acc1[4*q+2], acc1[4*q+3] };
        *(f4*)&lds[tid * LDS_STRIDE + q * 4] = r;
    }
    __syncthreads();
    #pragma unroll
    for (int k = 0; k < 4; ++k) {
        int flat = k * 1024 + tid * 4;
        int pix  = flat >> 4;
        int e    = flat & 15;
        f4 v = *(const f4*)&lds[pix * LDS_STRIDE + e];
        __builtin_nontemporal_store(v, o4 + 1024 + k * 256 + tid);
    }
}

// ---------- fallback (f32 gather, no ws) ----------

__global__ __launch_bounds__(256) void render_f32_kernel(
    const float* __restrict__ attributes,
    const float* __restrict__ bary,
    const int*   __restrict__ faces,
    const int*   __restrict__ p2f,
    float* __restrict__ out,
    float* __restrict__ mask)
{
    int i = blockIdx.x * blockDim.x + threadIdx.x;
    if (i >= HW_PIX) return;
    int pf = p2f[i];
    mask[i] = (pf != -1) ? 1.0f : 0.0f;
    int f = (pf < 0) ? pf + F_FACES : pf;
    int v0 = faces[f*3+0], v1 = faces[f*3+1], v2 = faces[f*3+2];
    float b0 = bary[i*3+0], b1 = bary[i*3+1], b2 = bary[i*3+2];
    const float4* a0 = (const float4*)(attributes + (size_t)v0 * D_ATTR);
    const float4* a1 = (const float4*)(attributes + (size_t)v1 * D_ATTR);
    const float4* a2 = (const float4*)(attributes + (size_t)v2 * D_ATTR);
    float4* o = (float4*)(out + (size_t)i * D_ATTR);
    #pragma unroll
    for (int q = 0; q < 4; ++q) {
        float4 p0 = a0[q], p1 = a1[q], p2 = a2[q], r;
        r.x = b0*p0.x + b1*p1.x + b2*p2.x;
        r.y = b0*p0.y + b1*p1.y + b2*p2.y;
        r.z = b0*p0.z + b1*p1.z + b2*p2.z;
        r.w = b0*p0.w + b1*p1.w + b2*p2.w;
        o[q] = r;
    }
}

extern "C" void kernel_launch(void* const* d_in, const int* in_sizes, int n_in,
                              void* d_out, int out_size, void* d_ws, size_t ws_size,
                              hipStream_t stream) {
    const float* attributes = (const float*)d_in[0];
    const float* bary       = (const float*)d_in[1];
    const int*   faces      = (const int*)d_in[2];
    const int*   p2f        = (const int*)d_in[3];

    float* out  = (float*)d_out;
    float* mask = (float*)d_out + (size_t)HW_PIX * D_ATTR;

    const size_t attrH_bytes = (size_t)V_VERTS * D_ATTR * 2;   // 3.2 MB
    const size_t pface_bytes = (size_t)F_FACES * 8;            // 1.6 MB
    dim3 block(256);

    if (ws_size >= attrH_bytes + pface_bytes) {
        __half* attrH = (__half*)d_ws;
        unsigned long long* pfaces =
            (unsigned long long*)((char*)d_ws + attrH_bytes);

        cvt_attr_kernel<<<(V_VERTS*D_ATTR/4 + 255)/256, block, 0, stream>>>(
            attributes, (__half2*)attrH);
        pack_faces_kernel<<<(F_FACES + 255)/256, block, 0, stream>>>(
            faces, pfaces);
        render_f16_kernel<<<HW_PIX / 512, block, 0, stream>>>(
            attrH, bary, pfaces, p2f, out, mask);
    } else {
        render_f32_kernel<<<(HW_PIX + 255)/256, block, 0, stream>>>(
            attributes, bary, faces, p2f, out, mask);
    }
}

// Round 10
// 57.375 us; speedup vs baseline: 1.0890x; 1.0890x over previous
//
#include <hip/hip_runtime.h>
#include <hip/hip_fp16.h>

#define HW_PIX (1024*1024)
#define D_ATTR 16
#define V_VERTS 100000
#define F_FACES 200000
#define LDS_STRIDE 20   // 16 floats + 4 pad
#define PXA 8           // pixels per thread in resolve phase
#define TA (HW_PIX / PXA)   // 131072 resolve threads

typedef float f4 __attribute__((ext_vector_type(4)));
typedef unsigned int u4 __attribute__((ext_vector_type(4)));

// ---------- pre-pass kernels ----------

__global__ __launch_bounds__(256) void cvt_attr_kernel(
    const float* __restrict__ in, __half2* __restrict__ out) {
    int i = blockIdx.x * blockDim.x + threadIdx.x;
    const int n = V_VERTS * D_ATTR / 4;
    if (i >= n) return;
    f4 v = __builtin_nontemporal_load((const f4*)in + i);
    out[i*2 + 0] = __floats2half2_rn(v.x, v.y);
    out[i*2 + 1] = __floats2half2_rn(v.z, v.w);
}

__global__ __launch_bounds__(256) void pack_faces_kernel(
    const int* __restrict__ faces, unsigned long long* __restrict__ pf) {
    int i = blockIdx.x * blockDim.x + threadIdx.x;
    if (i >= F_FACES) return;
    unsigned long long v0 = (unsigned)__builtin_nontemporal_load(faces + i*3 + 0);
    unsigned long long v1 = (unsigned)__builtin_nontemporal_load(faces + i*3 + 1);
    unsigned long long v2 = (unsigned)__builtin_nontemporal_load(faces + i*3 + 2);
    pf[i] = v0 | (v1 << 17) | (v2 << 34);
}

// ---------- phase A: resolve p2f -> per-pixel vertex indices ----------
// hot table: pfaces (1.6 MB, solo L2-resident). 8 gathers in flight/thread.

__global__ __launch_bounds__(256) void resolve_kernel(
    const int* __restrict__ p2f,                     // HW int32 (nt stream)
    const unsigned long long* __restrict__ pfaces,   // F packed (hot)
    unsigned long long* __restrict__ vidx,           // HW u64 (nt stream out)
    float* __restrict__ mask)                        // HW f32 (nt stream out)
{
    int t = blockIdx.x * 256 + threadIdx.x;          // 0..TA-1

    int f[PXA];
    #pragma unroll
    for (int k = 0; k < PXA; ++k) {
        int i = t + k * TA;
        int pf = __builtin_nontemporal_load(p2f + i);
        __builtin_nontemporal_store((pf != -1) ? 1.0f : 0.0f, mask + i);
        f[k] = (pf < 0) ? pf + F_FACES : pf;
    }

    unsigned long long u[PXA];
    #pragma unroll
    for (int k = 0; k < PXA; ++k)
        u[k] = pfaces[f[k]];                          // 8 independent gathers

    #pragma unroll
    for (int k = 0; k < PXA; ++k)
        __builtin_nontemporal_store(u[k], vidx + t + k * TA);
}

// ---------- phase B: shade (attr gather only; 3.2 MB resident) ----------

__device__ inline void cvt2(unsigned int w, float* f) {
    __half2 h = __builtin_bit_cast(__half2, w);
    float2 t = __half22float2(h);
    f[0] = t.x; f[1] = t.y;
}

__device__ inline void cvt8(u4 q, float* f) {
    cvt2(q.x, f + 0);
    cvt2(q.y, f + 2);
    cvt2(q.z, f + 4);
    cvt2(q.w, f + 6);
}

__global__ __launch_bounds__(256) void shade_kernel(
    const __half* __restrict__ attrH,               // V x 16 f16 (hot, resident)
    const float* __restrict__ bary,                 // HW x 3 f32 (nt stream)
    const unsigned long long* __restrict__ vidx,    // HW u64 (nt stream)
    float* __restrict__ out)                        // HW x 16 f32 (nt, full-line)
{
    __shared__ __align__(16) float lds[256 * LDS_STRIDE];

    int tid = threadIdx.x;
    int i = blockIdx.x * 256 + tid;

    unsigned long long u = __builtin_nontemporal_load(vidx + i);
    int v0 = (int)(u & 0x1FFFF);
    int v1 = (int)((u >> 17) & 0x1FFFF);
    int v2 = (int)((u >> 34) & 0x1FFFF);

    float b0 = __builtin_nontemporal_load(bary + i*3 + 0);
    float b1 = __builtin_nontemporal_load(bary + i*3 + 1);
    float b2 = __builtin_nontemporal_load(bary + i*3 + 2);

    const u4* A0 = (const u4*)(attrH + (size_t)v0 * D_ATTR);
    const u4* A1 = (const u4*)(attrH + (size_t)v1 * D_ATTR);
    const u4* A2 = (const u4*)(attrH + (size_t)v2 * D_ATTR);

    u4 r0a = A0[0], r0b = A0[1];
    u4 r1a = A1[0], r1b = A1[1];
    u4 r2a = A2[0], r2b = A2[1];

    float x0[16], x1[16], x2[16];
    cvt8(r0a, x0); cvt8(r0b, x0 + 8);
    cvt8(r1a, x1); cvt8(r1b, x1 + 8);
    cvt8(r2a, x2); cvt8(r2b, x2 + 8);

    #pragma unroll
    for (int q = 0; q < 4; ++q) {
        f4 r = { b0*x0[4*q+0] + b1*x1[4*q+0] + b2*x2[4*q+0],
                 b0*x0[4*q+1] + b1*x1[4*q+1] + b2*x2[4*q+1],
                 b0*x0[4*q+2] + b1*x1[4*q+2] + b2*x2[4*q+2],
                 b0*x0[4*q+3] + b1*x1[4*q+3] + b2*x2[4*q+3] };
        *(f4*)&lds[tid * LDS_STRIDE + q * 4] = r;
    }

    __syncthreads();

    f4* oblk = (f4*)out + (size_t)blockIdx.x * 1024;   // 256 px * 4 quads
    #pragma unroll
    for (int k = 0; k < 4; ++k) {
        int flat = k * 1024 + tid * 4;
        int pix  = flat >> 4;
        int e    = flat & 15;
        f4 v = *(const f4*)&lds[pix * LDS_STRIDE + e];
        __builtin_nontemporal_store(v, oblk + k * 256 + tid);
    }
}

// ---------- mid fallback: fused f16 kernel (R7 structure) ----------

__global__ __launch_bounds__(256) void render_f16_kernel(
    const __half* __restrict__ attrH,
    const float* __restrict__ bary,
    const unsigned long long* __restrict__ pfaces,
    const int* __restrict__ p2f,
    float* __restrict__ out,
    float* __restrict__ mask)
{
    __shared__ __align__(16) float lds[256 * LDS_STRIDE];

    int tid = threadIdx.x;
    int i = blockIdx.x * 256 + tid;

    int pf = __builtin_nontemporal_load(p2f + i);
    __builtin_nontemporal_store((pf != -1) ? 1.0f : 0.0f, mask + i);
    int f = (pf < 0) ? pf + F_FACES : pf;

    unsigned long long u = pfaces[f];
    int v0 = (int)(u & 0x1FFFF);
    int v1 = (int)((u >> 17) & 0x1FFFF);
    int v2 = (int)((u >> 34) & 0x1FFFF);

    float b0 = __builtin_nontemporal_load(bary + i*3 + 0);
    float b1 = __builtin_nontemporal_load(bary + i*3 + 1);
    float b2 = __builtin_nontemporal_load(bary + i*3 + 2);

    const u4* A0 = (const u4*)(attrH + (size_t)v0 * D_ATTR);
    const u4* A1 = (const u4*)(attrH + (size_t)v1 * D_ATTR);
    const u4* A2 = (const u4*)(attrH + (size_t)v2 * D_ATTR);

    u4 r0a = A0[0], r0b = A0[1];
    u4 r1a = A1[0], r1b = A1[1];
    u4 r2a = A2[0], r2b = A2[1];

    float x0[16], x1[16], x2[16];
    cvt8(r0a, x0); cvt8(r0b, x0 + 8);
    cvt8(r1a, x1); cvt8(r1b, x1 + 8);
    cvt8(r2a, x2); cvt8(r2b, x2 + 8);

    #pragma unroll
    for (int q = 0; q < 4; ++q) {
        f4 r = { b0*x0[4*q+0] + b1*x1[4*q+0] + b2*x2[4*q+0],
                 b0*x0[4*q+1] + b1*x1[4*q+1] + b2*x2[4*q+1],
                 b0*x0[4*q+2] + b1*x1[4*q+2] + b2*x2[4*q+2],
                 b0*x0[4*q+3] + b1*x1[4*q+3] + b2*x2[4*q+3] };
        *(f4*)&lds[tid * LDS_STRIDE + q * 4] = r;
    }
    __syncthreads();
    f4* oblk = (f4*)out + (size_t)blockIdx.x * 1024;
    #pragma unroll
    for (int k = 0; k < 4; ++k) {
        int flat = k * 1024 + tid * 4;
        int pix  = flat >> 4;
        int e    = flat & 15;
        f4 v = *(const f4*)&lds[pix * LDS_STRIDE + e];
        __builtin_nontemporal_store(v, oblk + k * 256 + tid);
    }
}

// ---------- last fallback (f32, no ws) ----------

__global__ __launch_bounds__(256) void render_f32_kernel(
    const float* __restrict__ attributes,
    const float* __restrict__ bary,
    const int*   __restrict__ faces,
    const int*   __restrict__ p2f,
    float* __restrict__ out,
    float* __restrict__ mask)
{
    int i = blockIdx.x * blockDim.x + threadIdx.x;
    if (i >= HW_PIX) return;
    int pf = p2f[i];
    mask[i] = (pf != -1) ? 1.0f : 0.0f;
    int f = (pf < 0) ? pf + F_FACES : pf;
    int v0 = faces[f*3+0], v1 = faces[f*3+1], v2 = faces[f*3+2];
    float b0 = bary[i*3+0], b1 = bary[i*3+1], b2 = bary[i*3+2];
    const float4* a0 = (const float4*)(attributes + (size_t)v0 * D_ATTR);
    const float4* a1 = (const float4*)(attributes + (size_t)v1 * D_ATTR);
    const float4* a2 = (const float4*)(attributes + (size_t)v2 * D_ATTR);
    float4* o = (float4*)(out + (size_t)i * D_ATTR);
    #pragma unroll
    for (int q = 0; q < 4; ++q) {
        float4 p0 = a0[q], p1 = a1[q], p2 = a2[q], r;
        r.x = b0*p0.x + b1*p1.x + b2*p2.x;
        r.y = b0*p0.y + b1*p1.y + b2*p2.y;
        r.z = b0*p0.z + b1*p1.z + b2*p2.z;
        r.w = b0*p0.w + b1*p1.w + b2*p2.w;
        o[q] = r;
    }
}

extern "C" void kernel_launch(void* const* d_in, const int* in_sizes, int n_in,
                              void* d_out, int out_size, void* d_ws, size_t ws_size,
                              hipStream_t stream) {
    const float* attributes = (const float*)d_in[0];
    const float* bary       = (const float*)d_in[1];
    const int*   faces      = (const int*)d_in[2];
    const int*   p2f        = (const int*)d_in[3];

    float* out  = (float*)d_out;
    float* mask = (float*)d_out + (size_t)HW_PIX * D_ATTR;

    const size_t attrH_bytes = (size_t)V_VERTS * D_ATTR * 2;   // 3.2 MB
    const size_t pface_bytes = (size_t)F_FACES * 8;            // 1.6 MB
    const size_t vidx_bytes  = (size_t)HW_PIX * 8;             // 8.0 MB
    dim3 block(256);

    if (ws_size >= attrH_bytes + pface_bytes + vidx_bytes) {
        __half* attrH = (__half*)d_ws;
        unsigned long long* pfaces =
            (unsigned long long*)((char*)d_ws + attrH_bytes);
        unsigned long long* vidx =
            (unsigned long long*)((char*)d_ws + attrH_bytes + pface_bytes);

        cvt_attr_kernel<<<(V_VERTS*D_ATTR/4 + 255)/256, block, 0, stream>>>(
            attributes, (__half2*)attrH);
        pack_faces_kernel<<<(F_FACES + 255)/256, block, 0, stream>>>(
            faces, pfaces);
        resolve_kernel<<<TA / 256, block, 0, stream>>>(
            p2f, pfaces, vidx, mask);
        shade_kernel<<<HW_PIX / 256, block, 0, stream>>>(
            attrH, bary, vidx, out);
    } else if (ws_size >= attrH_bytes + pface_bytes) {
        __half* attrH = (__half*)d_ws;
        unsigned long long* pfaces =
            (unsigned long long*)((char*)d_ws + attrH_bytes);
        cvt_attr_kernel<<<(V_VERTS*D_ATTR/4 + 255)/256, block, 0, stream>>>(
            attributes, (__half2*)attrH);
        pack_faces_kernel<<<(F_FACES + 255)/256, block, 0, stream>>>(
            faces, pfaces);
        render_f16_kernel<<<HW_PIX / 256, block, 0, stream>>>(
            attrH, bary, pfaces, p2f, out, mask);
    } else {
        render_f32_kernel<<<(HW_PIX + 255)/256, block, 0, stream>>>(
            attributes, bary, faces, p2f, out, mask);
    }
}